// Round 17
// baseline (440.774 us; speedup 1.0000x reference)
//
#include <hip/hip_runtime.h>
#include <cstdint>
#include <cstddef>

#define H 512
#define SEQ 128

typedef __bf16 v8bf __attribute__((ext_vector_type(8)));
typedef float v4f __attribute__((ext_vector_type(4)));
typedef unsigned short v8us __attribute__((ext_vector_type(8)));

__device__ __forceinline__ unsigned short f2bf(float f) {
    unsigned int u = __float_as_uint(f);
    u = (u + 0x7FFFu + ((u >> 16) & 1u)) >> 16;
    return (unsigned short)u;
}
__device__ __forceinline__ float bf2f(unsigned short h) {
    return __uint_as_float(((unsigned int)h) << 16);
}
__device__ __forceinline__ v8bf load_bf8(const unsigned short* p) {
    return *reinterpret_cast<const v8bf*>(p);
}
__device__ __forceinline__ float fast_tanh(float v) {
    float e = __expf(2.f * v);
    return 1.f - 2.f * __builtin_amdgcn_rcpf(e + 1.f);
}
__device__ __forceinline__ float fast_sigmoid(float v) {
    return __builtin_amdgcn_rcpf(1.f + __expf(-v));
}
__device__ __forceinline__ v8us cvt8u(float4 lo, float4 hi) {
    v8us r;
    r[0] = f2bf(lo.x); r[1] = f2bf(lo.y); r[2] = f2bf(lo.z); r[3] = f2bf(lo.w);
    r[4] = f2bf(hi.x); r[5] = f2bf(hi.y); r[6] = f2bf(hi.z); r[7] = f2bf(hi.w);
    return r;
}

// Swizzled B layout: frag[((c*16 + ks)*64 + lane)*8 + j] = W[g][k]
//   g = c*16 + (lane&15),  k = ks*32 + (lane>>4)*8 + j

// ---------------------------------------------------------------------------
// prep: build swizzled WyS (Wl[:, :512]), WiS (Wl[:, 512:]), WaS (Wa1^T)
// ---------------------------------------------------------------------------
__global__ __launch_bounds__(256) void prep_kernel(
        const float* __restrict__ Wa1, const float* __restrict__ Wl,
        unsigned short* __restrict__ WyS, unsigned short* __restrict__ WiS,
        unsigned short* __restrict__ WaS) {
    int tg = blockIdx.x * 256 + threadIdx.x;   // 0..98303
    int mat = tg >> 15;
    int idx = tg & 32767;
    int lane = idx & 63;
    int ks = (idx >> 6) & 15;
    int c = idx >> 10;
    int g = c * 16 + (lane & 15);
    int hb = ks * 32 + ((lane >> 4) << 3);
    unsigned short o[8];
    unsigned short* dst;
    if (mat == 0) {
        const float* s = Wl + (size_t)g * 1024 + hb;
#pragma unroll
        for (int j = 0; j < 8; ++j) o[j] = f2bf(s[j]);
        dst = WyS + (size_t)idx * 8;
    } else if (mat == 1) {
        const float* s = Wl + (size_t)g * 1024 + 512 + hb;
#pragma unroll
        for (int j = 0; j < 8; ++j) o[j] = f2bf(s[j]);
        dst = WiS + (size_t)idx * 8;
    } else {
#pragma unroll
        for (int j = 0; j < 8; ++j) o[j] = f2bf(Wa1[(size_t)(hb + j) * H + g]);
        dst = WaS + (size_t)idx * 8;
    }
    *reinterpret_cast<ushort4*>(dst)     = *reinterpret_cast<ushort4*>(&o[0]);
    *reinterpret_cast<ushort4*>(dst + 4) = *reinterpret_cast<ushort4*>(&o[4]);
}

// ---------------------------------------------------------------------------
// attn_pool v3: TWO (b,s) tiles per block (tiles 2k, 2k+1) -> WaS L2 stream
// halves (520 -> 260 MB); wave = 2 tiles x 32 rows x 128 cols, acc[2][2][8]
// = 128 AGPR (2x MFMA per B-fragment).  508 blocks, 256 thr.
// ---------------------------------------------------------------------------
__global__ __launch_bounds__(256, 2) void attn_pool_kernel(
        const float* __restrict__ x, const unsigned short* __restrict__ WaS,
        const float* __restrict__ ba1, const float* __restrict__ wa2,
        float* __restrict__ ixf, unsigned short* __restrict__ ixb) {
    __shared__ __align__(16) unsigned short Xb[2][32][520];
    __shared__ float attn_s[64];
    __shared__ float scpart[4][64];

    int bid = blockIdx.x;                // 0..507
    int t = threadIdx.x;

    // stage both tiles
#pragma unroll
    for (int tt = 0; tt < 2; ++tt) {
        int tile = bid * 2 + tt;
        int b = tile / 127, s = tile % 127;
        const float4* x4 = reinterpret_cast<const float4*>(
            x + (size_t)(b * SEQ + s) * 32 * H);
#pragma unroll
        for (int i = 0; i < 16; ++i) {
            int idx4 = t + i * 256;
            float4 v = x4[idx4];
            int e = idx4 * 4, m = e >> 9, h = e & 511;
            ushort4 o;
            o.x = f2bf(v.x); o.y = f2bf(v.y); o.z = f2bf(v.z); o.w = f2bf(v.w);
            *reinterpret_cast<ushort4*>(&Xb[tt][m][h]) = o;
        }
    }
    __syncthreads();

    int w = t >> 6, lane = t & 63, q = lane >> 4, c16 = lane & 15;

    v4f acc[2][2][8];
#pragma unroll
    for (int tt = 0; tt < 2; ++tt)
#pragma unroll
        for (int mi = 0; mi < 2; ++mi)
#pragma unroll
            for (int ci = 0; ci < 8; ++ci) acc[tt][mi][ci] = (v4f){0.f, 0.f, 0.f, 0.f};

    const unsigned short* Bb = WaS + (size_t)(w * 8 * 16) * 512 + lane * 8;

#pragma unroll
    for (int ks = 0; ks < 16; ++ks) {
        v8bf a[2][2];
#pragma unroll
        for (int tt = 0; tt < 2; ++tt)
#pragma unroll
            for (int mi = 0; mi < 2; ++mi)
                a[tt][mi] = load_bf8(&Xb[tt][mi * 16 + c16][ks * 32 + q * 8]);
#pragma unroll
        for (int ci = 0; ci < 8; ++ci) {
            v8bf bb = load_bf8(Bb + (size_t)(ci * 16 + ks) * 512);
#pragma unroll
            for (int tt = 0; tt < 2; ++tt)
#pragma unroll
                for (int mi = 0; mi < 2; ++mi)
                    acc[tt][mi][ci] = __builtin_amdgcn_mfma_f32_16x16x32_bf16(
                        a[tt][mi], bb, acc[tt][mi][ci], 0, 0, 0);
        }
    }

    float sr[2][2][4];
#pragma unroll
    for (int tt = 0; tt < 2; ++tt)
#pragma unroll
        for (int mi = 0; mi < 2; ++mi)
#pragma unroll
            for (int i = 0; i < 4; ++i) sr[tt][mi][i] = 0.f;

#pragma unroll
    for (int ci = 0; ci < 8; ++ci) {
        int g = (w * 8 + ci) * 16 + c16;
        float w2 = wa2[g];
        float bv = ba1[g];
#pragma unroll
        for (int tt = 0; tt < 2; ++tt)
#pragma unroll
            for (int mi = 0; mi < 2; ++mi)
#pragma unroll
                for (int i = 0; i < 4; ++i)
                    sr[tt][mi][i] += w2 * fast_tanh(acc[tt][mi][ci][i] + bv);
    }
#pragma unroll
    for (int off = 1; off < 16; off <<= 1) {
#pragma unroll
        for (int tt = 0; tt < 2; ++tt)
#pragma unroll
            for (int mi = 0; mi < 2; ++mi)
#pragma unroll
                for (int i = 0; i < 4; ++i) sr[tt][mi][i] += __shfl_xor(sr[tt][mi][i], off);
    }
    if (c16 == 0) {
#pragma unroll
        for (int tt = 0; tt < 2; ++tt)
#pragma unroll
            for (int mi = 0; mi < 2; ++mi)
#pragma unroll
                for (int i = 0; i < 4; ++i)
                    scpart[w][tt * 32 + mi * 16 + q * 4 + i] = sr[tt][mi][i];
    }
    __syncthreads();

    // wave-parallel softmax: lanes 0-31 = tile0, lanes 32-63 = tile1
    // (shfl_xor off<32 stays within each 32-lane half).
    if (t < 64) {
        int m = t & 31, tile = t >> 5;
        int e0 = tile * 32 + m;
        float v = scpart[0][e0] + scpart[1][e0] + scpart[2][e0] + scpart[3][e0];
        float mx = v;
#pragma unroll
        for (int off = 1; off < 32; off <<= 1) mx = fmaxf(mx, __shfl_xor(mx, off));
        float e = __expf(v - mx);
        float sum = e;
#pragma unroll
        for (int off = 1; off < 32; off <<= 1) sum += __shfl_xor(sum, off);
        attn_s[e0] = e * __builtin_amdgcn_rcpf(sum);
    }
    __syncthreads();

    int h0 = t * 2;
#pragma unroll
    for (int tt = 0; tt < 2; ++tt) {
        float p0 = 0.f, p1 = 0.f;
#pragma unroll
        for (int m = 0; m < 32; ++m) {
            float am = attn_s[tt * 32 + m];
            p0 += am * bf2f(Xb[tt][m][h0]);
            p1 += am * bf2f(Xb[tt][m][h0 + 1]);
        }
        size_t r = (size_t)(bid * 2 + tt);
        ixf[r * H + h0] = p0;
        ixf[r * H + h0 + 1] = p1;
        ixb[r * H + h0] = f2bf(p0);
        ixb[r * H + h0 + 1] = f2bf(p1);
    }
}

// ---------------------------------------------------------------------------
// ipre: i_pre[r,g] = sum_h i_x[r,h] * Wi[g,h] + bl[g]   (r < 1016)
// ---------------------------------------------------------------------------
__global__ __launch_bounds__(256) void ipre_kernel(
        const unsigned short* __restrict__ ixb, const unsigned short* __restrict__ WiS,
        const float* __restrict__ bl, float* __restrict__ ipre) {
    int row16 = blockIdx.x * 16;
    int t = threadIdx.x, w = t >> 6, lane = t & 63, q = lane >> 4, c16 = lane & 15;
    int c0 = blockIdx.y * 8 + w * 2;

    v4f acc0 = {0.f, 0.f, 0.f, 0.f};
    v4f acc1 = {0.f, 0.f, 0.f, 0.f};
    const unsigned short* arow = ixb + (size_t)(row16 + c16) * H + q * 8;
#pragma unroll
    for (int ks = 0; ks < 16; ++ks) {
        v8bf a = load_bf8(arow + ks * 32);
        acc0 = __builtin_amdgcn_mfma_f32_16x16x32_bf16(
            a, load_bf8(WiS + (size_t)(c0 * 16 + ks) * 512 + lane * 8), acc0, 0, 0, 0);
        acc1 = __builtin_amdgcn_mfma_f32_16x16x32_bf16(
            a, load_bf8(WiS + (size_t)((c0 + 1) * 16 + ks) * 512 + lane * 8), acc1, 0, 0, 0);
    }
#pragma unroll
    for (int cc = 0; cc < 2; ++cc) {
        int g = (c0 + cc) * 16 + c16;
        float blv = bl[g];
        v4f a = cc ? acc1 : acc0;
#pragma unroll
        for (int i = 0; i < 4; ++i) {
            int row = row16 + q * 4 + i;
            if (row < 1016) ipre[(size_t)row * H + g] = a[i] + blv;
        }
    }
}

// ---------------------------------------------------------------------------
// main v16 = r16 config + 3 blocks/CU: LDS 57344 -> 51200 (A pad 40->36
// shorts — stride 72B hits 16 distinct banks; ip/ix read direct from L2-hot
// global in epilogue), __launch_bounds__(512,6).  Three independent barrier
// streams per CU overlap each other's vmcnt-drain stalls.
// ---------------------------------------------------------------------------
__global__ __launch_bounds__(512, 6) void main_kernel(
        const float* __restrict__ y, const unsigned short* __restrict__ WyS,
        const float* __restrict__ ixf, const float* __restrict__ ipre,
        float* __restrict__ out) {
    int bid0 = blockIdx.x;
    int t = threadIdx.x;

    if (bid0 >= 1016) {
        // s==0 passthrough: 16 blocks, each copies 32 rows x 512 cols f32.
        int cb = bid0 - 1016;            // 0..15
        int b = cb >> 1, half = cb & 1;
        size_t base = ((size_t)(b * SEQ)) * 64 * H + (size_t)half * 32 * H;
        const float4* y4 = reinterpret_cast<const float4*>(y + base);
        float4* o4 = reinterpret_cast<float4*>(out + base);
#pragma unroll
        for (int i = 0; i < 8; ++i) o4[t + i * 512] = y4[t + i * 512];
        return;
    }

    // bijective XCD swizzle: 1016 = 8 * 127 (exact)
    int bid = (bid0 & 7) * 127 + (bid0 >> 3);

    int rg = bid >> 1;                   // row-group: 128 rows = tiles 2rg, 2rg+1
    int ch = bid & 1;                    // col half: g in [ch*256, ch*256+256)

    __shared__ __align__(16) char arena[51200];
    unsigned short* Ab = (unsigned short*)arena;             // [2][128*36] = 9216 B each
    unsigned short* Bbuf = (unsigned short*)(arena + 18432); // [2][16*512] = 16384 B each
    float* ep = (float*)arena;                               // epilogue alias [32][260]

    int t0 = rg * 2;

    // ---- per-thread A staging assignment (fixed row, 8 f32 per phase) ----
    int arow  = t >> 2;                  // 0..127
    int acol0 = (t & 3) * 8;             // 0,8,16,24
    int atid  = t0 + (arow >> 6);
    int ab    = atid / 127, asm1 = atid % 127;
    const float* yrow = y + ((size_t)(ab * SEQ + asm1 + 1) * 64 + (arow & 63)) * H;

    // ---- per-thread B staging assignment (2 chunks of 16B per phase) ----
    int w = t >> 6, lane = t & 63, q = lane >> 4, c16 = lane & 15;
    int ck0 = w * 2;                     // chunks ck0, ck0+1 (0..15)
    const unsigned short* bsrc0 = WyS + (size_t)((ch * 16 + ck0) * 16) * 512 + lane * 8;
    const unsigned short* bsrc1 = WyS + (size_t)((ch * 16 + ck0 + 1) * 16) * 512 + lane * 8;

    // in-flight register sets: set[k] holds loads for phase p with (p&1)==k
    float4 a_lo[2], a_hi[2]; v8us b0r[2], b1r[2];

    // ---- prologue: phase 0 staged directly; phase 1 loads issued ----
    {
        float4 a0 = *reinterpret_cast<const float4*>(yrow + acol0);
        float4 a1 = *reinterpret_cast<const float4*>(yrow + acol0 + 4);
        v8us b0 = *reinterpret_cast<const v8us*>(bsrc0);
        v8us b1 = *reinterpret_cast<const v8us*>(bsrc1);
        a_lo[1] = *reinterpret_cast<const float4*>(yrow + 32 + acol0);
        a_hi[1] = *reinterpret_cast<const float4*>(yrow + 32 + acol0 + 4);
        b0r[1] = *reinterpret_cast<const v8us*>(bsrc0 + 512);
        b1r[1] = *reinterpret_cast<const v8us*>(bsrc1 + 512);
        *reinterpret_cast<v8us*>(&Ab[arow * 36 + acol0]) = cvt8u(a0, a1);
        *reinterpret_cast<v8us*>(&Bbuf[ck0 * 512 + lane * 8]) = b0;
        *reinterpret_cast<v8us*>(&Bbuf[(ck0 + 1) * 512 + lane * 8]) = b1;
    }
    __syncthreads();

    int wr = w >> 1;                     // 0..3  row-group within block
    int wc = w & 1;                      // 0..1  col-half within block's 256

    v4f acc[2][8];
#pragma unroll
    for (int rt = 0; rt < 2; ++rt)
#pragma unroll
        for (int ci = 0; ci < 8; ++ci) acc[rt][ci] = (v4f){0.f, 0.f, 0.f, 0.f};

    // ---- main K loop: 16 phases, dbuf, 2-deep prefetch ----
#pragma unroll
    for (int p = 0; p < 16; ++p) {
        const int cur = p & 1;
        const int nxt = cur ^ 1;
        if (p < 14) {
            a_lo[cur] = *reinterpret_cast<const float4*>(yrow + (p + 2) * 32 + acol0);
            a_hi[cur] = *reinterpret_cast<const float4*>(yrow + (p + 2) * 32 + acol0 + 4);
            b0r[cur] = *reinterpret_cast<const v8us*>(bsrc0 + (p + 2) * 512);
            b1r[cur] = *reinterpret_cast<const v8us*>(bsrc1 + (p + 2) * 512);
        }
        if (p < 15) {
            *reinterpret_cast<v8us*>(&Ab[nxt * 4608 + arow * 36 + acol0]) =
                cvt8u(a_lo[nxt], a_hi[nxt]);
            *reinterpret_cast<v8us*>(&Bbuf[nxt * 8192 + ck0 * 512 + lane * 8]) = b0r[nxt];
            *reinterpret_cast<v8us*>(&Bbuf[nxt * 8192 + (ck0 + 1) * 512 + lane * 8]) = b1r[nxt];
        }

        v8bf af0 = load_bf8(&Ab[cur * 4608 + (wr * 32 + c16) * 36 + q * 8]);
        v8bf af1 = load_bf8(&Ab[cur * 4608 + (wr * 32 + 16 + c16) * 36 + q * 8]);
#pragma unroll
        for (int ci = 0; ci < 8; ++ci) {
            v8bf bf = load_bf8(&Bbuf[cur * 8192 + (wc * 8 + ci) * 512 + lane * 8]);
            acc[0][ci] = __builtin_amdgcn_mfma_f32_16x16x32_bf16(af0, bf, acc[0][ci], 0, 0, 0);
            acc[1][ci] = __builtin_amdgcn_mfma_f32_16x16x32_bf16(af1, bf, acc[1][ci], 0, 0, 0);
        }

        if (p < 15) __syncthreads();
    }

    // ---- coalesced epilogue via LDS transpose, 4 slabs of 32 rows ----
    int tile = wr >> 1;                  // wave-uniform
    size_t obase0 = ((size_t)((t0 / 127) * SEQ + t0 % 127 + 1) * 64) * H;
    size_t obase1 = ((size_t)(((t0 + 1) / 127) * SEQ + (t0 + 1) % 127 + 1) * 64) * H;

    // per-lane ip/ix from L2-hot global (replaces LDS stage; saves 4KB LDS)
    float ipr[8], ixr[8];
#pragma unroll
    for (int ci = 0; ci < 8; ++ci) {
        int gl = wc * 128 + ci * 16 + c16;
        size_t rr = (size_t)(t0 + tile) * H + ch * 256 + gl;
        ipr[ci] = ipre[rr];
        ixr[ci] = ixf[rr];
    }

#pragma unroll
    for (int slab = 0; slab < 4; ++slab) {
        __syncthreads();   // slab 0: also protects Ab/Bbuf still read by K-loop
        if (wr == slab) {
#pragma unroll
            for (int ci = 0; ci < 8; ++ci) {
                int gl = wc * 128 + ci * 16 + c16;        // 0..255
#pragma unroll
                for (int rt = 0; rt < 2; ++rt)
#pragma unroll
                    for (int i = 0; i < 4; ++i) {
                        int rl = rt * 16 + q * 4 + i;     // 0..31 within slab
                        ep[rl * 260 + gl] = ixr[ci] * fast_sigmoid(acc[rt][ci][i] + ipr[ci]);
                    }
            }
        }
        __syncthreads();
        // cooperative coalesced store: 32 rows x 256 f32 = 2048 float4
#pragma unroll
        for (int k = 0; k < 4; ++k) {
            int c = t + k * 512;                  // 0..2047
            int rl = c >> 6;                      // 0..31
            int cx = (c & 63) * 4;                // col f32 within 256
            int browg = slab * 32 + rl;           // 0..127
            int tl = browg >> 6;
            int n = browg & 63;
            size_t off = (tl ? obase1 : obase0) + (size_t)n * H + ch * 256 + cx;
            float4 g4 = *reinterpret_cast<const float4*>(&ep[rl * 260 + cx]);
            float4 y4 = *reinterpret_cast<const float4*>(&y[off]);
            float4 o;
            o.x = y4.x + g4.x; o.y = y4.y + g4.y;
            o.z = y4.z + g4.z; o.w = y4.w + g4.w;
            *reinterpret_cast<float4*>(&out[off]) = o;
        }
    }
}

// ---------------------------------------------------------------------------
extern "C" void kernel_launch(void* const* d_in, const int* in_sizes, int n_in,
                              void* d_out, int out_size, void* d_ws, size_t ws_size,
                              hipStream_t stream) {
    const float* x   = (const float*)d_in[0];
    const float* y   = (const float*)d_in[1];
    const float* Wa1 = (const float*)d_in[2];
    const float* ba1 = (const float*)d_in[3];
    const float* wa2 = (const float*)d_in[4];
    const float* Wl  = (const float*)d_in[5];
    const float* bl  = (const float*)d_in[6];
    float* out = (float*)d_out;

    char* ws = (char*)d_ws;
    unsigned short* WyS  = (unsigned short*)(ws);                     // 512 KB
    unsigned short* WiS  = (unsigned short*)(ws + 524288);            // 512 KB
    unsigned short* WaS  = (unsigned short*)(ws + 1048576);           // 512 KB
    float*          ixf  = (float*)(ws + 1572864);                    // 2 MB (1024 rows)
    unsigned short* ixb  = (unsigned short*)(ws + 3670016);           // 1 MB (1024 rows)
    float*          ipre = (float*)(ws + 4718592);                    // 2 MB (1024 rows)

    hipLaunchKernelGGL(prep_kernel, dim3(384), dim3(256), 0, stream, Wa1, Wl, WyS, WiS, WaS);
    hipLaunchKernelGGL(attn_pool_kernel, dim3(508), dim3(256), 0, stream,
                       x, WaS, ba1, wa2, ixf, ixb);
    hipLaunchKernelGGL(ipre_kernel, dim3(64, 4), dim3(256), 0, stream, ixb, WiS, bl, ipre);
    hipLaunchKernelGGL(main_kernel, dim3(1032), dim3(512), 0, stream,
                       y, WyS, ixf, ipre, out);
}

// Round 18
// 158.804 us; speedup vs baseline: 2.7756x; 2.7756x over previous
//
#include <hip/hip_runtime.h>
#include <cstdint>
#include <cstddef>

#define H 512
#define SEQ 128

typedef __bf16 v8bf __attribute__((ext_vector_type(8)));
typedef float v4f __attribute__((ext_vector_type(4)));
typedef unsigned short v8us __attribute__((ext_vector_type(8)));

__device__ __forceinline__ unsigned short f2bf(float f) {
    unsigned int u = __float_as_uint(f);
    u = (u + 0x7FFFu + ((u >> 16) & 1u)) >> 16;
    return (unsigned short)u;
}
__device__ __forceinline__ float bf2f(unsigned short h) {
    return __uint_as_float(((unsigned int)h) << 16);
}
__device__ __forceinline__ v8bf load_bf8(const unsigned short* p) {
    return *reinterpret_cast<const v8bf*>(p);
}
__device__ __forceinline__ float fast_tanh(float v) {
    float e = __expf(2.f * v);
    return 1.f - 2.f * __builtin_amdgcn_rcpf(e + 1.f);
}
__device__ __forceinline__ float fast_sigmoid(float v) {
    return __builtin_amdgcn_rcpf(1.f + __expf(-v));
}
__device__ __forceinline__ v8us cvt8u(float4 lo, float4 hi) {
    v8us r;
    r[0] = f2bf(lo.x); r[1] = f2bf(lo.y); r[2] = f2bf(lo.z); r[3] = f2bf(lo.w);
    r[4] = f2bf(hi.x); r[5] = f2bf(hi.y); r[6] = f2bf(hi.z); r[7] = f2bf(hi.w);
    return r;
}

// Swizzled B layout: frag[((c*16 + ks)*64 + lane)*8 + j] = W[g][k]
//   g = c*16 + (lane&15),  k = ks*32 + (lane>>4)*8 + j

// ---------------------------------------------------------------------------
// prep: build swizzled WyS (Wl[:, :512]), WiS (Wl[:, 512:]), WaS (Wa1^T)
// ---------------------------------------------------------------------------
__global__ __launch_bounds__(256) void prep_kernel(
        const float* __restrict__ Wa1, const float* __restrict__ Wl,
        unsigned short* __restrict__ WyS, unsigned short* __restrict__ WiS,
        unsigned short* __restrict__ WaS) {
    int tg = blockIdx.x * 256 + threadIdx.x;   // 0..98303
    int mat = tg >> 15;
    int idx = tg & 32767;
    int lane = idx & 63;
    int ks = (idx >> 6) & 15;
    int c = idx >> 10;
    int g = c * 16 + (lane & 15);
    int hb = ks * 32 + ((lane >> 4) << 3);
    unsigned short o[8];
    unsigned short* dst;
    if (mat == 0) {
        const float* s = Wl + (size_t)g * 1024 + hb;
#pragma unroll
        for (int j = 0; j < 8; ++j) o[j] = f2bf(s[j]);
        dst = WyS + (size_t)idx * 8;
    } else if (mat == 1) {
        const float* s = Wl + (size_t)g * 1024 + 512 + hb;
#pragma unroll
        for (int j = 0; j < 8; ++j) o[j] = f2bf(s[j]);
        dst = WiS + (size_t)idx * 8;
    } else {
#pragma unroll
        for (int j = 0; j < 8; ++j) o[j] = f2bf(Wa1[(size_t)(hb + j) * H + g]);
        dst = WaS + (size_t)idx * 8;
    }
    *reinterpret_cast<ushort4*>(dst)     = *reinterpret_cast<ushort4*>(&o[0]);
    *reinterpret_cast<ushort4*>(dst + 4) = *reinterpret_cast<ushort4*>(&o[4]);
}

// ---------------------------------------------------------------------------
// attn_pool v3: TWO (b,s) tiles per block (tiles 2k, 2k+1) -> WaS L2 stream
// halves (520 -> 260 MB); wave = 2 tiles x 32 rows x 128 cols, acc[2][2][8]
// = 128 AGPR (2x MFMA per B-fragment).  508 blocks, 256 thr.
// ---------------------------------------------------------------------------
__global__ __launch_bounds__(256, 2) void attn_pool_kernel(
        const float* __restrict__ x, const unsigned short* __restrict__ WaS,
        const float* __restrict__ ba1, const float* __restrict__ wa2,
        float* __restrict__ ixf, unsigned short* __restrict__ ixb) {
    __shared__ __align__(16) unsigned short Xb[2][32][520];
    __shared__ float attn_s[64];
    __shared__ float scpart[4][64];

    int bid = blockIdx.x;                // 0..507
    int t = threadIdx.x;

    // stage both tiles
#pragma unroll
    for (int tt = 0; tt < 2; ++tt) {
        int tile = bid * 2 + tt;
        int b = tile / 127, s = tile % 127;
        const float4* x4 = reinterpret_cast<const float4*>(
            x + (size_t)(b * SEQ + s) * 32 * H);
#pragma unroll
        for (int i = 0; i < 16; ++i) {
            int idx4 = t + i * 256;
            float4 v = x4[idx4];
            int e = idx4 * 4, m = e >> 9, h = e & 511;
            ushort4 o;
            o.x = f2bf(v.x); o.y = f2bf(v.y); o.z = f2bf(v.z); o.w = f2bf(v.w);
            *reinterpret_cast<ushort4*>(&Xb[tt][m][h]) = o;
        }
    }
    __syncthreads();

    int w = t >> 6, lane = t & 63, q = lane >> 4, c16 = lane & 15;

    v4f acc[2][2][8];
#pragma unroll
    for (int tt = 0; tt < 2; ++tt)
#pragma unroll
        for (int mi = 0; mi < 2; ++mi)
#pragma unroll
            for (int ci = 0; ci < 8; ++ci) acc[tt][mi][ci] = (v4f){0.f, 0.f, 0.f, 0.f};

    const unsigned short* Bb = WaS + (size_t)(w * 8 * 16) * 512 + lane * 8;

#pragma unroll
    for (int ks = 0; ks < 16; ++ks) {
        v8bf a[2][2];
#pragma unroll
        for (int tt = 0; tt < 2; ++tt)
#pragma unroll
            for (int mi = 0; mi < 2; ++mi)
                a[tt][mi] = load_bf8(&Xb[tt][mi * 16 + c16][ks * 32 + q * 8]);
#pragma unroll
        for (int ci = 0; ci < 8; ++ci) {
            v8bf bb = load_bf8(Bb + (size_t)(ci * 16 + ks) * 512);
#pragma unroll
            for (int tt = 0; tt < 2; ++tt)
#pragma unroll
                for (int mi = 0; mi < 2; ++mi)
                    acc[tt][mi][ci] = __builtin_amdgcn_mfma_f32_16x16x32_bf16(
                        a[tt][mi], bb, acc[tt][mi][ci], 0, 0, 0);
        }
    }

    float sr[2][2][4];
#pragma unroll
    for (int tt = 0; tt < 2; ++tt)
#pragma unroll
        for (int mi = 0; mi < 2; ++mi)
#pragma unroll
            for (int i = 0; i < 4; ++i) sr[tt][mi][i] = 0.f;

#pragma unroll
    for (int ci = 0; ci < 8; ++ci) {
        int g = (w * 8 + ci) * 16 + c16;
        float w2 = wa2[g];
        float bv = ba1[g];
#pragma unroll
        for (int tt = 0; tt < 2; ++tt)
#pragma unroll
            for (int mi = 0; mi < 2; ++mi)
#pragma unroll
                for (int i = 0; i < 4; ++i)
                    sr[tt][mi][i] += w2 * fast_tanh(acc[tt][mi][ci][i] + bv);
    }
#pragma unroll
    for (int off = 1; off < 16; off <<= 1) {
#pragma unroll
        for (int tt = 0; tt < 2; ++tt)
#pragma unroll
            for (int mi = 0; mi < 2; ++mi)
#pragma unroll
                for (int i = 0; i < 4; ++i) sr[tt][mi][i] += __shfl_xor(sr[tt][mi][i], off);
    }
    if (c16 == 0) {
#pragma unroll
        for (int tt = 0; tt < 2; ++tt)
#pragma unroll
            for (int mi = 0; mi < 2; ++mi)
#pragma unroll
                for (int i = 0; i < 4; ++i)
                    scpart[w][tt * 32 + mi * 16 + q * 4 + i] = sr[tt][mi][i];
    }
    __syncthreads();

    // wave-parallel softmax: lanes 0-31 = tile0, lanes 32-63 = tile1.
    if (t < 64) {
        int m = t & 31, tile = t >> 5;
        int e0 = tile * 32 + m;
        float v = scpart[0][e0] + scpart[1][e0] + scpart[2][e0] + scpart[3][e0];
        float mx = v;
#pragma unroll
        for (int off = 1; off < 32; off <<= 1) mx = fmaxf(mx, __shfl_xor(mx, off));
        float e = __expf(v - mx);
        float sum = e;
#pragma unroll
        for (int off = 1; off < 32; off <<= 1) sum += __shfl_xor(sum, off);
        attn_s[e0] = e * __builtin_amdgcn_rcpf(sum);
    }
    __syncthreads();

    int h0 = t * 2;
#pragma unroll
    for (int tt = 0; tt < 2; ++tt) {
        float p0 = 0.f, p1 = 0.f;
#pragma unroll
        for (int m = 0; m < 32; ++m) {
            float am = attn_s[tt * 32 + m];
            p0 += am * bf2f(Xb[tt][m][h0]);
            p1 += am * bf2f(Xb[tt][m][h0 + 1]);
        }
        size_t r = (size_t)(bid * 2 + tt);
        ixf[r * H + h0] = p0;
        ixf[r * H + h0 + 1] = p1;
        ixb[r * H + h0] = f2bf(p0);
        ixb[r * H + h0 + 1] = f2bf(p1);
    }
}

// ---------------------------------------------------------------------------
// ipre: i_pre[r,g] = sum_h i_x[r,h] * Wi[g,h] + bl[g]   (r < 1016)
// ---------------------------------------------------------------------------
__global__ __launch_bounds__(256) void ipre_kernel(
        const unsigned short* __restrict__ ixb, const unsigned short* __restrict__ WiS,
        const float* __restrict__ bl, float* __restrict__ ipre) {
    int row16 = blockIdx.x * 16;
    int t = threadIdx.x, w = t >> 6, lane = t & 63, q = lane >> 4, c16 = lane & 15;
    int c0 = blockIdx.y * 8 + w * 2;

    v4f acc0 = {0.f, 0.f, 0.f, 0.f};
    v4f acc1 = {0.f, 0.f, 0.f, 0.f};
    const unsigned short* arow = ixb + (size_t)(row16 + c16) * H + q * 8;
#pragma unroll
    for (int ks = 0; ks < 16; ++ks) {
        v8bf a = load_bf8(arow + ks * 32);
        acc0 = __builtin_amdgcn_mfma_f32_16x16x32_bf16(
            a, load_bf8(WiS + (size_t)(c0 * 16 + ks) * 512 + lane * 8), acc0, 0, 0, 0);
        acc1 = __builtin_amdgcn_mfma_f32_16x16x32_bf16(
            a, load_bf8(WiS + (size_t)((c0 + 1) * 16 + ks) * 512 + lane * 8), acc1, 0, 0, 0);
    }
#pragma unroll
    for (int cc = 0; cc < 2; ++cc) {
        int g = (c0 + cc) * 16 + c16;
        float blv = bl[g];
        v4f a = cc ? acc1 : acc0;
#pragma unroll
        for (int i = 0; i < 4; ++i) {
            int row = row16 + q * 4 + i;
            if (row < 1016) ipre[(size_t)row * H + g] = a[i] + blv;
        }
    }
}

// ---------------------------------------------------------------------------
// main v15 (r16-EXACT, measured 104us): 128x256 block, (512,4), LDS 57344,
// 2-deep prefetch, bijective XCD swizzle, coalesced LDS epilogue.
// r17's (512,6) spilled (85-reg budget < 64 AGPR + staging) — 2 blocks/CU is
// the hard ceiling for 512-thr blocks with a 64-AGPR accumulator.
// ---------------------------------------------------------------------------
__global__ __launch_bounds__(512, 4) void main_kernel(
        const float* __restrict__ y, const unsigned short* __restrict__ WyS,
        const float* __restrict__ ixf, const float* __restrict__ ipre,
        float* __restrict__ out) {
    int bid0 = blockIdx.x;
    int t = threadIdx.x;

    if (bid0 >= 1016) {
        // s==0 passthrough: 16 blocks, each copies 32 rows x 512 cols f32.
        int cb = bid0 - 1016;            // 0..15
        int b = cb >> 1, half = cb & 1;
        size_t base = ((size_t)(b * SEQ)) * 64 * H + (size_t)half * 32 * H;
        const float4* y4 = reinterpret_cast<const float4*>(y + base);
        float4* o4 = reinterpret_cast<float4*>(out + base);
#pragma unroll
        for (int i = 0; i < 8; ++i) o4[t + i * 512] = y4[t + i * 512];
        return;
    }

    // bijective XCD swizzle: 1016 = 8 * 127 (exact)
    int bid = (bid0 & 7) * 127 + (bid0 >> 3);

    int rg = bid >> 1;                   // row-group: 128 rows = tiles 2rg, 2rg+1
    int ch = bid & 1;                    // col half: g in [ch*256, ch*256+256)

    __shared__ __align__(16) char arena[57344];
    unsigned short* Ab = (unsigned short*)arena;             // [2][128*40] bf16
    unsigned short* Bbuf = (unsigned short*)(arena + 20480); // [2][16*512] bf16
    float* ip_s = (float*)(arena + 53248);                   // [512]
    float* ix_s = (float*)(arena + 55296);                   // [512]
    float* ep   = (float*)arena;                             // epilogue alias [32][260]

    int t0 = rg * 2;

    // ---- per-thread A staging assignment (fixed row, 8 f32 per phase) ----
    int arow  = t >> 2;                  // 0..127
    int acol0 = (t & 3) * 8;             // 0,8,16,24
    int atid  = t0 + (arow >> 6);
    int ab    = atid / 127, asm1 = atid % 127;
    const float* yrow = y + ((size_t)(ab * SEQ + asm1 + 1) * 64 + (arow & 63)) * H;

    // ---- per-thread B staging assignment (2 chunks of 16B per phase) ----
    int w = t >> 6, lane = t & 63, q = lane >> 4, c16 = lane & 15;
    int ck0 = w * 2;                     // chunks ck0, ck0+1 (0..15)
    const unsigned short* bsrc0 = WyS + (size_t)((ch * 16 + ck0) * 16) * 512 + lane * 8;
    const unsigned short* bsrc1 = WyS + (size_t)((ch * 16 + ck0 + 1) * 16) * 512 + lane * 8;

    // ---- ip/ix staging (once) ----
    {
        int tile = t >> 8, gl = t & 255;
        size_t rrow = (size_t)(t0 + tile) * H + ch * 256 + gl;
        ip_s[t] = ipre[rrow];
        ix_s[t] = ixf[rrow];
    }

    // in-flight register sets: set[k] holds loads for phase p with (p&1)==k
    float4 a_lo[2], a_hi[2]; v8us b0r[2], b1r[2];

    // ---- prologue: phase 0 staged directly; phase 1 loads issued ----
    {
        float4 a0 = *reinterpret_cast<const float4*>(yrow + acol0);
        float4 a1 = *reinterpret_cast<const float4*>(yrow + acol0 + 4);
        v8us b0 = *reinterpret_cast<const v8us*>(bsrc0);
        v8us b1 = *reinterpret_cast<const v8us*>(bsrc1);
        a_lo[1] = *reinterpret_cast<const float4*>(yrow + 32 + acol0);
        a_hi[1] = *reinterpret_cast<const float4*>(yrow + 32 + acol0 + 4);
        b0r[1] = *reinterpret_cast<const v8us*>(bsrc0 + 512);
        b1r[1] = *reinterpret_cast<const v8us*>(bsrc1 + 512);
        *reinterpret_cast<v8us*>(&Ab[arow * 40 + acol0]) = cvt8u(a0, a1);
        *reinterpret_cast<v8us*>(&Bbuf[ck0 * 512 + lane * 8]) = b0;
        *reinterpret_cast<v8us*>(&Bbuf[(ck0 + 1) * 512 + lane * 8]) = b1;
    }
    __syncthreads();

    int wr = w >> 1;                     // 0..3  row-group within block
    int wc = w & 1;                      // 0..1  col-half within block's 256

    v4f acc[2][8];
#pragma unroll
    for (int rt = 0; rt < 2; ++rt)
#pragma unroll
        for (int ci = 0; ci < 8; ++ci) acc[rt][ci] = (v4f){0.f, 0.f, 0.f, 0.f};

    // ---- main K loop: 16 phases, dbuf, 2-deep prefetch ----
#pragma unroll
    for (int p = 0; p < 16; ++p) {
        const int cur = p & 1;
        const int nxt = cur ^ 1;
        if (p < 14) {
            a_lo[cur] = *reinterpret_cast<const float4*>(yrow + (p + 2) * 32 + acol0);
            a_hi[cur] = *reinterpret_cast<const float4*>(yrow + (p + 2) * 32 + acol0 + 4);
            b0r[cur] = *reinterpret_cast<const v8us*>(bsrc0 + (p + 2) * 512);
            b1r[cur] = *reinterpret_cast<const v8us*>(bsrc1 + (p + 2) * 512);
        }
        if (p < 15) {
            *reinterpret_cast<v8us*>(&Ab[nxt * 5120 + arow * 40 + acol0]) =
                cvt8u(a_lo[nxt], a_hi[nxt]);
            *reinterpret_cast<v8us*>(&Bbuf[nxt * 8192 + ck0 * 512 + lane * 8]) = b0r[nxt];
            *reinterpret_cast<v8us*>(&Bbuf[nxt * 8192 + (ck0 + 1) * 512 + lane * 8]) = b1r[nxt];
        }

        v8bf af0 = load_bf8(&Ab[cur * 5120 + (wr * 32 + c16) * 40 + q * 8]);
        v8bf af1 = load_bf8(&Ab[cur * 5120 + (wr * 32 + 16 + c16) * 40 + q * 8]);
#pragma unroll
        for (int ci = 0; ci < 8; ++ci) {
            v8bf bf = load_bf8(&Bbuf[cur * 8192 + (wc * 8 + ci) * 512 + lane * 8]);
            acc[0][ci] = __builtin_amdgcn_mfma_f32_16x16x32_bf16(af0, bf, acc[0][ci], 0, 0, 0);
            acc[1][ci] = __builtin_amdgcn_mfma_f32_16x16x32_bf16(af1, bf, acc[1][ci], 0, 0, 0);
        }

        if (p < 15) __syncthreads();
    }

    // ---- coalesced epilogue via LDS transpose, 4 slabs of 32 rows ----
    int tile = wr >> 1;                  // wave-uniform
    size_t obase0 = ((size_t)((t0 / 127) * SEQ + t0 % 127 + 1) * 64) * H;
    size_t obase1 = ((size_t)(((t0 + 1) / 127) * SEQ + (t0 + 1) % 127 + 1) * 64) * H;

#pragma unroll
    for (int slab = 0; slab < 4; ++slab) {
        __syncthreads();   // slab 0: also protects Ab/Bbuf still read by K-loop
        if (wr == slab) {
#pragma unroll
            for (int ci = 0; ci < 8; ++ci) {
                int gl = wc * 128 + ci * 16 + c16;        // 0..255
                float ip = ip_s[tile * 256 + gl];
                float ixv = ix_s[tile * 256 + gl];
#pragma unroll
                for (int rt = 0; rt < 2; ++rt)
#pragma unroll
                    for (int i = 0; i < 4; ++i) {
                        int rl = rt * 16 + q * 4 + i;     // 0..31 within slab
                        ep[rl * 260 + gl] = ixv * fast_sigmoid(acc[rt][ci][i] + ip);
                    }
            }
        }
        __syncthreads();
        // cooperative coalesced store: 32 rows x 256 f32 = 2048 float4
#pragma unroll
        for (int k = 0; k < 4; ++k) {
            int c = t + k * 512;                  // 0..2047
            int rl = c >> 6;                      // 0..31
            int cx = (c & 63) * 4;                // col f32 within 256
            int browg = slab * 32 + rl;           // 0..127
            int tl = browg >> 6;
            int n = browg & 63;
            size_t off = (tl ? obase1 : obase0) + (size_t)n * H + ch * 256 + cx;
            float4 g4 = *reinterpret_cast<const float4*>(&ep[rl * 260 + cx]);
            float4 y4 = *reinterpret_cast<const float4*>(&y[off]);
            float4 o;
            o.x = y4.x + g4.x; o.y = y4.y + g4.y;
            o.z = y4.z + g4.z; o.w = y4.w + g4.w;
            *reinterpret_cast<float4*>(&out[off]) = o;
        }
    }
}

// ---------------------------------------------------------------------------
extern "C" void kernel_launch(void* const* d_in, const int* in_sizes, int n_in,
                              void* d_out, int out_size, void* d_ws, size_t ws_size,
                              hipStream_t stream) {
    const float* x   = (const float*)d_in[0];
    const float* y   = (const float*)d_in[1];
    const float* Wa1 = (const float*)d_in[2];
    const float* ba1 = (const float*)d_in[3];
    const float* wa2 = (const float*)d_in[4];
    const float* Wl  = (const float*)d_in[5];
    const float* bl  = (const float*)d_in[6];
    float* out = (float*)d_out;

    char* ws = (char*)d_ws;
    unsigned short* WyS  = (unsigned short*)(ws);                     // 512 KB
    unsigned short* WiS  = (unsigned short*)(ws + 524288);            // 512 KB
    unsigned short* WaS  = (unsigned short*)(ws + 1048576);           // 512 KB
    float*          ixf  = (float*)(ws + 1572864);                    // 2 MB (1024 rows)
    unsigned short* ixb  = (unsigned short*)(ws + 3670016);           // 1 MB (1024 rows)
    float*          ipre = (float*)(ws + 4718592);                    // 2 MB (1024 rows)

    hipLaunchKernelGGL(prep_kernel, dim3(384), dim3(256), 0, stream, Wa1, Wl, WyS, WiS, WaS);
    hipLaunchKernelGGL(attn_pool_kernel, dim3(508), dim3(256), 0, stream,
                       x, WaS, ba1, wa2, ixf, ixb);
    hipLaunchKernelGGL(ipre_kernel, dim3(64, 4), dim3(256), 0, stream, ixb, WiS, bl, ipre);
    hipLaunchKernelGGL(main_kernel, dim3(1032), dim3(512), 0, stream,
                       y, WyS, ixf, ipre, out);
}

// Round 20
// 144.898 us; speedup vs baseline: 3.0420x; 1.0960x over previous
//
#include <hip/hip_runtime.h>
#include <cstdint>
#include <cstddef>

#define H 512
#define SEQ 128

typedef __bf16 v8bf __attribute__((ext_vector_type(8)));
typedef float v4f __attribute__((ext_vector_type(4)));
typedef unsigned short v8us __attribute__((ext_vector_type(8)));

__device__ __forceinline__ unsigned short f2bf(float f) {
    unsigned int u = __float_as_uint(f);
    u = (u + 0x7FFFu + ((u >> 16) & 1u)) >> 16;
    return (unsigned short)u;
}
__device__ __forceinline__ float bf2f(unsigned short h) {
    return __uint_as_float(((unsigned int)h) << 16);
}
__device__ __forceinline__ v8bf load_bf8(const unsigned short* p) {
    return *reinterpret_cast<const v8bf*>(p);
}
__device__ __forceinline__ float fast_tanh(float v) {
    float e = __expf(2.f * v);
    return 1.f - 2.f * __builtin_amdgcn_rcpf(e + 1.f);
}
__device__ __forceinline__ float fast_sigmoid(float v) {
    return __builtin_amdgcn_rcpf(1.f + __expf(-v));
}
__device__ __forceinline__ v8us cvt8u(float4 lo, float4 hi) {
    v8us r;
    r[0] = f2bf(lo.x); r[1] = f2bf(lo.y); r[2] = f2bf(lo.z); r[3] = f2bf(lo.w);
    r[4] = f2bf(hi.x); r[5] = f2bf(hi.y); r[6] = f2bf(hi.z); r[7] = f2bf(hi.w);
    return r;
}

// Swizzled B layout: frag[((c*16 + ks)*64 + lane)*8 + j] = W[g][k]
//   g = c*16 + (lane&15),  k = ks*32 + (lane>>4)*8 + j

// ---------------------------------------------------------------------------
// prep: build swizzled WyS (Wl[:, :512]), WiS (Wl[:, 512:]), WaS (Wa1^T)
// ---------------------------------------------------------------------------
__global__ __launch_bounds__(256) void prep_kernel(
        const float* __restrict__ Wa1, const float* __restrict__ Wl,
        unsigned short* __restrict__ WyS, unsigned short* __restrict__ WiS,
        unsigned short* __restrict__ WaS) {
    int tg = blockIdx.x * 256 + threadIdx.x;   // 0..98303
    int mat = tg >> 15;
    int idx = tg & 32767;
    int lane = idx & 63;
    int ks = (idx >> 6) & 15;
    int c = idx >> 10;
    int g = c * 16 + (lane & 15);
    int hb = ks * 32 + ((lane >> 4) << 3);
    unsigned short o[8];
    unsigned short* dst;
    if (mat == 0) {
        const float* s = Wl + (size_t)g * 1024 + hb;
#pragma unroll
        for (int j = 0; j < 8; ++j) o[j] = f2bf(s[j]);
        dst = WyS + (size_t)idx * 8;
    } else if (mat == 1) {
        const float* s = Wl + (size_t)g * 1024 + 512 + hb;
#pragma unroll
        for (int j = 0; j < 8; ++j) o[j] = f2bf(s[j]);
        dst = WiS + (size_t)idx * 8;
    } else {
#pragma unroll
        for (int j = 0; j < 8; ++j) o[j] = f2bf(Wa1[(size_t)(hb + j) * H + g]);
        dst = WaS + (size_t)idx * 8;
    }
    *reinterpret_cast<ushort4*>(dst)     = *reinterpret_cast<ushort4*>(&o[0]);
    *reinterpret_cast<ushort4*>(dst + 4) = *reinterpret_cast<ushort4*>(&o[4]);
}

// ---------------------------------------------------------------------------
// attn_pool v1 (best measured; v2 no-stage and v3 2-tile both regressed).
// One block per (b, s<127).  wave = 32 rows x 128 cols, acc 2x8.
// ---------------------------------------------------------------------------
__global__ __launch_bounds__(256, 4) void attn_pool_kernel(
        const float* __restrict__ x, const unsigned short* __restrict__ WaS,
        const float* __restrict__ ba1, const float* __restrict__ wa2,
        float* __restrict__ ixf, unsigned short* __restrict__ ixb) {
    __shared__ __align__(16) unsigned short Xb[32][520];
    __shared__ float attn[32];
    __shared__ float scpart[4][32];

    int bid = blockIdx.x;
    int b = bid / 127, s = bid % 127;
    int t = threadIdx.x;

    const float4* x4 = reinterpret_cast<const float4*>(x + (size_t)(b * SEQ + s) * 32 * H);
#pragma unroll
    for (int i = 0; i < 16; ++i) {
        int idx4 = t + i * 256;
        float4 v = x4[idx4];
        int e = idx4 * 4, m = e >> 9, h = e & 511;
        ushort4 o;
        o.x = f2bf(v.x); o.y = f2bf(v.y); o.z = f2bf(v.z); o.w = f2bf(v.w);
        *reinterpret_cast<ushort4*>(&Xb[m][h]) = o;
    }
    __syncthreads();

    int w = t >> 6, lane = t & 63, q = lane >> 4, c16 = lane & 15;

    v4f acc[2][8];
#pragma unroll
    for (int mi = 0; mi < 2; ++mi)
#pragma unroll
        for (int ci = 0; ci < 8; ++ci) acc[mi][ci] = (v4f){0.f, 0.f, 0.f, 0.f};

    const unsigned short* Bb = WaS + (size_t)(w * 8 * 16) * 512 + lane * 8;

#pragma unroll
    for (int ks = 0; ks < 16; ++ks) {
        v8bf a0 = load_bf8(&Xb[c16][ks * 32 + q * 8]);
        v8bf a1 = load_bf8(&Xb[16 + c16][ks * 32 + q * 8]);
#pragma unroll
        for (int ci = 0; ci < 8; ++ci) {
            v8bf bb = load_bf8(Bb + (size_t)(ci * 16 + ks) * 512);
            acc[0][ci] = __builtin_amdgcn_mfma_f32_16x16x32_bf16(a0, bb, acc[0][ci], 0, 0, 0);
            acc[1][ci] = __builtin_amdgcn_mfma_f32_16x16x32_bf16(a1, bb, acc[1][ci], 0, 0, 0);
        }
    }

    float sr[2][4] = {{0.f, 0.f, 0.f, 0.f}, {0.f, 0.f, 0.f, 0.f}};
#pragma unroll
    for (int ci = 0; ci < 8; ++ci) {
        int g = (w * 8 + ci) * 16 + c16;
        float w2 = wa2[g];
        float bv = ba1[g];
#pragma unroll
        for (int mi = 0; mi < 2; ++mi)
#pragma unroll
            for (int i = 0; i < 4; ++i)
                sr[mi][i] += w2 * fast_tanh(acc[mi][ci][i] + bv);
    }
#pragma unroll
    for (int off = 1; off < 16; off <<= 1) {
#pragma unroll
        for (int mi = 0; mi < 2; ++mi)
#pragma unroll
            for (int i = 0; i < 4; ++i) sr[mi][i] += __shfl_xor(sr[mi][i], off);
    }
    if (c16 == 0) {
#pragma unroll
        for (int mi = 0; mi < 2; ++mi)
#pragma unroll
            for (int i = 0; i < 4; ++i) scpart[w][mi * 16 + q * 4 + i] = sr[mi][i];
    }
    __syncthreads();

    if (t < 64) {
        int m = t & 31;
        float v = scpart[0][m] + scpart[1][m] + scpart[2][m] + scpart[3][m];
        float mx = v;
#pragma unroll
        for (int off = 1; off < 32; off <<= 1) mx = fmaxf(mx, __shfl_xor(mx, off));
        float e = __expf(v - mx);
        float sum = e;
#pragma unroll
        for (int off = 1; off < 32; off <<= 1) sum += __shfl_xor(sum, off);
        if (t < 32) attn[m] = e * __builtin_amdgcn_rcpf(sum);
    }
    __syncthreads();

    int h0 = t * 2;
    float p0 = 0.f, p1 = 0.f;
#pragma unroll
    for (int m = 0; m < 32; ++m) {
        float am = attn[m];
        p0 += am * bf2f(Xb[m][h0]);
        p1 += am * bf2f(Xb[m][h0 + 1]);
    }
    size_t r = (size_t)bid;
    ixf[r * H + h0] = p0;
    ixf[r * H + h0 + 1] = p1;
    ixb[r * H + h0] = f2bf(p0);
    ixb[r * H + h0 + 1] = f2bf(p1);
}

// ---------------------------------------------------------------------------
// ipre: i_pre[r,g] = sum_h i_x[r,h] * Wi[g,h] + bl[g]   (r < 1016)
// ---------------------------------------------------------------------------
__global__ __launch_bounds__(256) void ipre_kernel(
        const unsigned short* __restrict__ ixb, const unsigned short* __restrict__ WiS,
        const float* __restrict__ bl, float* __restrict__ ipre) {
    int row16 = blockIdx.x * 16;
    int t = threadIdx.x, w = t >> 6, lane = t & 63, q = lane >> 4, c16 = lane & 15;
    int c0 = blockIdx.y * 8 + w * 2;

    v4f acc0 = {0.f, 0.f, 0.f, 0.f};
    v4f acc1 = {0.f, 0.f, 0.f, 0.f};
    const unsigned short* arow = ixb + (size_t)(row16 + c16) * H + q * 8;
#pragma unroll
    for (int ks = 0; ks < 16; ++ks) {
        v8bf a = load_bf8(arow + ks * 32);
        acc0 = __builtin_amdgcn_mfma_f32_16x16x32_bf16(
            a, load_bf8(WiS + (size_t)(c0 * 16 + ks) * 512 + lane * 8), acc0, 0, 0, 0);
        acc1 = __builtin_amdgcn_mfma_f32_16x16x32_bf16(
            a, load_bf8(WiS + (size_t)((c0 + 1) * 16 + ks) * 512 + lane * 8), acc1, 0, 0, 0);
    }
#pragma unroll
    for (int cc = 0; cc < 2; ++cc) {
        int g = (c0 + cc) * 16 + c16;
        float blv = bl[g];
        v4f a = cc ? acc1 : acc0;
#pragma unroll
        for (int i = 0; i < 4; ++i) {
            int row = row16 + q * 4 + i;
            if (row < 1016) ipre[(size_t)row * H + g] = a[i] + blv;
        }
    }
}

// ---------------------------------------------------------------------------
// main v15 (r16-EXACT, measured 104us): 128x256 block, (512,4), LDS 57344,
// 2-deep prefetch, bijective XCD swizzle, coalesced LDS epilogue.
// ---------------------------------------------------------------------------
__global__ __launch_bounds__(512, 4) void main_kernel(
        const float* __restrict__ y, const unsigned short* __restrict__ WyS,
        const float* __restrict__ ixf, const float* __restrict__ ipre,
        float* __restrict__ out) {
    int bid0 = blockIdx.x;
    int t = threadIdx.x;

    if (bid0 >= 1016) {
        // s==0 passthrough: 16 blocks, each copies 32 rows x 512 cols f32.
        int cb = bid0 - 1016;            // 0..15
        int b = cb >> 1, half = cb & 1;
        size_t base = ((size_t)(b * SEQ)) * 64 * H + (size_t)half * 32 * H;
        const float4* y4 = reinterpret_cast<const float4*>(y + base);
        float4* o4 = reinterpret_cast<float4*>(out + base);
#pragma unroll
        for (int i = 0; i < 8; ++i) o4[t + i * 512] = y4[t + i * 512];
        return;
    }

    // bijective XCD swizzle: 1016 = 8 * 127 (exact)
    int bid = (bid0 & 7) * 127 + (bid0 >> 3);

    int rg = bid >> 1;                   // row-group: 128 rows = tiles 2rg, 2rg+1
    int ch = bid & 1;                    // col half: g in [ch*256, ch*256+256)

    __shared__ __align__(16) char arena[57344];
    unsigned short* Ab = (unsigned short*)arena;             // [2][128*40] bf16
    unsigned short* Bbuf = (unsigned short*)(arena + 20480); // [2][16*512] bf16
    float* ip_s = (float*)(arena + 53248);                   // [512]
    float* ix_s = (float*)(arena + 55296);                   // [512]
    float* ep   = (float*)arena;                             // epilogue alias [32][260]

    int t0 = rg * 2;

    // ---- per-thread A staging assignment (fixed row, 8 f32 per phase) ----
    int arow  = t >> 2;                  // 0..127
    int acol0 = (t & 3) * 8;             // 0,8,16,24
    int atid  = t0 + (arow >> 6);
    int ab    = atid / 127, asm1 = atid % 127;
    const float* yrow = y + ((size_t)(ab * SEQ + asm1 + 1) * 64 + (arow & 63)) * H;

    // ---- per-thread B staging assignment (2 chunks of 16B per phase) ----
    int w = t >> 6, lane = t & 63, q = lane >> 4, c16 = lane & 15;
    int ck0 = w * 2;                     // chunks ck0, ck0+1 (0..15)
    const unsigned short* bsrc0 = WyS + (size_t)((ch * 16 + ck0) * 16) * 512 + lane * 8;
    const unsigned short* bsrc1 = WyS + (size_t)((ch * 16 + ck0 + 1) * 16) * 512 + lane * 8;

    // ---- ip/ix staging (once) ----
    {
        int tile = t >> 8, gl = t & 255;
        size_t rrow = (size_t)(t0 + tile) * H + ch * 256 + gl;
        ip_s[t] = ipre[rrow];
        ix_s[t] = ixf[rrow];
    }

    // in-flight register sets: set[k] holds loads for phase p with (p&1)==k
    float4 a_lo[2], a_hi[2]; v8us b0r[2], b1r[2];

    // ---- prologue: phase 0 staged directly; phase 1 loads issued ----
    {
        float4 a0 = *reinterpret_cast<const float4*>(yrow + acol0);
        float4 a1 = *reinterpret_cast<const float4*>(yrow + acol0 + 4);
        v8us b0 = *reinterpret_cast<const v8us*>(bsrc0);
        v8us b1 = *reinterpret_cast<const v8us*>(bsrc1);
        a_lo[1] = *reinterpret_cast<const float4*>(yrow + 32 + acol0);
        a_hi[1] = *reinterpret_cast<const float4*>(yrow + 32 + acol0 + 4);
        b0r[1] = *reinterpret_cast<const v8us*>(bsrc0 + 512);
        b1r[1] = *reinterpret_cast<const v8us*>(bsrc1 + 512);
        *reinterpret_cast<v8us*>(&Ab[arow * 40 + acol0]) = cvt8u(a0, a1);
        *reinterpret_cast<v8us*>(&Bbuf[ck0 * 512 + lane * 8]) = b0;
        *reinterpret_cast<v8us*>(&Bbuf[(ck0 + 1) * 512 + lane * 8]) = b1;
    }
    __syncthreads();

    int wr = w >> 1;                     // 0..3  row-group within block
    int wc = w & 1;                      // 0..1  col-half within block's 256

    v4f acc[2][8];
#pragma unroll
    for (int rt = 0; rt < 2; ++rt)
#pragma unroll
        for (int ci = 0; ci < 8; ++ci) acc[rt][ci] = (v4f){0.f, 0.f, 0.f, 0.f};

    // ---- main K loop: 16 phases, dbuf, 2-deep prefetch ----
#pragma unroll
    for (int p = 0; p < 16; ++p) {
        const int cur = p & 1;
        const int nxt = cur ^ 1;
        if (p < 14) {
            a_lo[cur] = *reinterpret_cast<const float4*>(yrow + (p + 2) * 32 + acol0);
            a_hi[cur] = *reinterpret_cast<const float4*>(yrow + (p + 2) * 32 + acol0 + 4);
            b0r[cur] = *reinterpret_cast<const v8us*>(bsrc0 + (p + 2) * 512);
            b1r[cur] = *reinterpret_cast<const v8us*>(bsrc1 + (p + 2) * 512);
        }
        if (p < 15) {
            *reinterpret_cast<v8us*>(&Ab[nxt * 5120 + arow * 40 + acol0]) =
                cvt8u(a_lo[nxt], a_hi[nxt]);
            *reinterpret_cast<v8us*>(&Bbuf[nxt * 8192 + ck0 * 512 + lane * 8]) = b0r[nxt];
            *reinterpret_cast<v8us*>(&Bbuf[nxt * 8192 + (ck0 + 1) * 512 + lane * 8]) = b1r[nxt];
        }

        v8bf af0 = load_bf8(&Ab[cur * 5120 + (wr * 32 + c16) * 40 + q * 8]);
        v8bf af1 = load_bf8(&Ab[cur * 5120 + (wr * 32 + 16 + c16) * 40 + q * 8]);
#pragma unroll
        for (int ci = 0; ci < 8; ++ci) {
            v8bf bf = load_bf8(&Bbuf[cur * 8192 + (wc * 8 + ci) * 512 + lane * 8]);
            acc[0][ci] = __builtin_amdgcn_mfma_f32_16x16x32_bf16(af0, bf, acc[0][ci], 0, 0, 0);
            acc[1][ci] = __builtin_amdgcn_mfma_f32_16x16x32_bf16(af1, bf, acc[1][ci], 0, 0, 0);
        }

        if (p < 15) __syncthreads();
    }

    // ---- coalesced epilogue via LDS transpose, 4 slabs of 32 rows ----
    int tile = wr >> 1;                  // wave-uniform
    size_t obase0 = ((size_t)((t0 / 127) * SEQ + t0 % 127 + 1) * 64) * H;
    size_t obase1 = ((size_t)(((t0 + 1) / 127) * SEQ + (t0 + 1) % 127 + 1) * 64) * H;

#pragma unroll
    for (int slab = 0; slab < 4; ++slab) {
        __syncthreads();   // slab 0: also protects Ab/Bbuf still read by K-loop
        if (wr == slab) {
#pragma unroll
            for (int ci = 0; ci < 8; ++ci) {
                int gl = wc * 128 + ci * 16 + c16;        // 0..255
                float ip = ip_s[tile * 256 + gl];
                float ixv = ix_s[tile * 256 + gl];
#pragma unroll
                for (int rt = 0; rt < 2; ++rt)
#pragma unroll
                    for (int i = 0; i < 4; ++i) {
                        int rl = rt * 16 + q * 4 + i;     // 0..31 within slab
                        ep[rl * 260 + gl] = ixv * fast_sigmoid(acc[rt][ci][i] + ip);
                    }
            }
        }
        __syncthreads();
        // cooperative coalesced store: 32 rows x 256 f32 = 2048 float4
#pragma unroll
        for (int k = 0; k < 4; ++k) {
            int c = t + k * 512;                  // 0..2047
            int rl = c >> 6;                      // 0..31
            int cx = (c & 63) * 4;                // col f32 within 256
            int browg = slab * 32 + rl;           // 0..127
            int tl = browg >> 6;
            int n = browg & 63;
            size_t off = (tl ? obase1 : obase0) + (size_t)n * H + ch * 256 + cx;
            float4 g4 = *reinterpret_cast<const float4*>(&ep[rl * 260 + cx]);
            float4 y4 = *reinterpret_cast<const float4*>(&y[off]);
            float4 o;
            o.x = y4.x + g4.x; o.y = y4.y + g4.y;
            o.z = y4.z + g4.z; o.w = y4.w + g4.w;
            *reinterpret_cast<float4*>(&out[off]) = o;
        }
    }
}

// ---------------------------------------------------------------------------
extern "C" void kernel_launch(void* const* d_in, const int* in_sizes, int n_in,
                              void* d_out, int out_size, void* d_ws, size_t ws_size,
                              hipStream_t stream) {
    const float* x   = (const float*)d_in[0];
    const float* y   = (const float*)d_in[1];
    const float* Wa1 = (const float*)d_in[2];
    const float* ba1 = (const float*)d_in[3];
    const float* wa2 = (const float*)d_in[4];
    const float* Wl  = (const float*)d_in[5];
    const float* bl  = (const float*)d_in[6];
    float* out = (float*)d_out;

    char* ws = (char*)d_ws;
    unsigned short* WyS  = (unsigned short*)(ws);                     // 512 KB
    unsigned short* WiS  = (unsigned short*)(ws + 524288);            // 512 KB
    unsigned short* WaS  = (unsigned short*)(ws + 1048576);           // 512 KB
    float*          ixf  = (float*)(ws + 1572864);                    // 2 MB (1024 rows)
    unsigned short* ixb  = (unsigned short*)(ws + 3670016);           // 1 MB (1024 rows)
    float*          ipre = (float*)(ws + 4718592);                    // 2 MB (1024 rows)

    hipLaunchKernelGGL(prep_kernel, dim3(384), dim3(256), 0, stream, Wa1, Wl, WyS, WiS, WaS);
    hipLaunchKernelGGL(attn_pool_kernel, dim3(1016), dim3(256), 0, stream,
                       x, WaS, ba1, wa2, ixf, ixb);
    hipLaunchKernelGGL(ipre_kernel, dim3(64, 4), dim3(256), 0, stream, ixb, WiS, bl, ipre);
    hipLaunchKernelGGL(main_kernel, dim3(1032), dim3(512), 0, stream,
                       y, WyS, ixf, ipre, out);
}